// Round 7
// baseline (132.691 us; speedup 1.0000x reference)
//
#include <hip/hip_runtime.h>
#include <hip/hip_cooperative_groups.h>
#include <math.h>

namespace cg = cooperative_groups;

#define NPTS   131072
#define BATCH  2
#define MBOX   128
#define NBOX   (BATCH * MBOX)       // 256
#define NFPS   512

#define GRID   64                   // 64x64 xy cells per batch
#define NCELL  (BATCH * GRID * GRID)   // 8192
#define CCAP   64                   // slots per cell (lambda ~16)
#define XMIN   (-75.2f)
#define INVCELL (64.0f / 150.4f)

#define NBLK   512
#define NTHR   256

// ws layout: cursor[NCELL] int (32 KB) | binned[NCELL*CCAP] float4 (8 MB)
#define BIN_OFF (NCELL * 4)

__global__ __launch_bounds__(NTHR)
void roi_all(const float* __restrict__ points,   // (N,4): [b,x,y,z]
             const float* __restrict__ boxes,    // (B,M,7)
             int* __restrict__ cursor,           // (NCELL)
             float4* __restrict__ binned,        // (NCELL, CCAP): x,y,z,idx
             int* __restrict__ out_idx,          // (NBOX, 512)
             int* __restrict__ out_num)          // (NBOX)
{
    cg::grid_group gg = cg::this_grid();
    const int tid  = threadIdx.x;
    const int gtid = blockIdx.x * NTHR + tid;    // 0..131071

    // ---- stage 0: zero cell cursors ----
    if (gtid < NCELL) cursor[gtid] = 0;
    gg.sync();

    // ---- stage A: bin one point per thread (order irrelevant) ----
    {
        const float4 p = ((const float4*)points)[gtid];
        const int b  = (int)p.x;                  // exact: 0.0f or 1.0f
        const int ix = min(GRID - 1, max(0, (int)floorf((p.y - XMIN) * INVCELL)));
        const int iy = min(GRID - 1, max(0, (int)floorf((p.z - XMIN) * INVCELL)));
        const int cell = b * GRID * GRID + iy * GRID + ix;
        const int slot = atomicAdd(&cursor[cell], 1);
        if (slot < CCAP)
            binned[cell * CCAP + slot] = make_float4(p.y, p.z, p.w, __int_as_float(gtid));
    }
    gg.sync();

    // ---- stage B: one block per box (blocks >= NBOX exit) ----
    const int box = blockIdx.x;
    if (box >= NBOX) return;

    const int lane = tid & 63;
    const int w    = tid >> 6;
    const int b    = box >> 7;                    // box / MBOX

    // bitmask over all N points, padded: dword d lives at d + d/16 (stride 17)
    __shared__ unsigned s_bits[NPTS / 32 + NPTS / 512];   // 4352 dwords
    __shared__ int s_cbase[64];
    __shared__ int s_ccnt[64];
    __shared__ int s_wsum[4];

    #pragma unroll
    for (int k = 0; k < 17; ++k) s_bits[tid + k * 256] = 0u;

    // box params -- fp32/f64 ops verbatim from the passing kernels (bit-exact)
    const float* bx = boxes + box * 7;
    const float cx = bx[0], cy = bx[1], cz = bx[2];
    const float bdx = bx[3], bdy = bx[4], bdz = bx[5], h = bx[6];
    const float hx = __fmul_rn(__fadd_rn(bdy, 2.0f), 0.5f);
    const float hy = __fmul_rn(__fadd_rn(bdx, 2.0f), 0.5f);
    const float hz = __fmul_rn(__fadd_rn(bdz, 2.0f), 0.5f);
    const float hp = -__fadd_rn(h, 1.5707963705062866f);  // fl32(pi/2)
    const float c = (float)cos((double)hp);
    const float s = (float)sin((double)hp);

    // conservative candidate AABB (superset; margin >> any fp slop)
    const float R = sqrtf(hx * hx + hy * hy) + 0.1f;
    const int ix0 = max(0, (int)floorf((cx - R - XMIN) * INVCELL));
    const int ix1 = min(GRID - 1, (int)floorf((cx + R - XMIN) * INVCELL));
    const int iy0 = max(0, (int)floorf((cy - R - XMIN) * INVCELL));
    const int iy1 = min(GRID - 1, (int)floorf((cy + R - XMIN) * INVCELL));
    const int nx = ix1 - ix0 + 1;
    const int nc = nx * (iy1 - iy0 + 1);          // <= ~36

    if (tid < nc) {
        const int gx = ix0 + tid % nx;
        const int gy = iy0 + tid / nx;
        const int cell = b * GRID * GRID + gy * GRID + gx;
        s_cbase[tid] = cell * CCAP;
        s_ccnt[tid]  = min(cursor[cell], CCAP);
    }
    __syncthreads();

    // scan candidate slots; set bits for exact-inside points
    const int nslots = nc * CCAP;
    for (int sl = tid; sl < nslots; sl += NTHR) {
        const int ci = sl / CCAP;
        const int k  = sl & (CCAP - 1);
        if (k < s_ccnt[ci]) {
            const float4 q = binned[s_cbase[ci] + k];
            const float ddx = __fsub_rn(q.x, cx);
            const float ddy = __fsub_rn(q.y, cy);
            const float ddz = __fsub_rn(q.z, cz);
            const float lx  = __fadd_rn(__fmul_rn(ddx, c), __fmul_rn(ddy, s));
            const float ly  = __fadd_rn(__fmul_rn(-ddx, s), __fmul_rn(ddy, c));
            if ((fabsf(lx) <= hx) & (fabsf(ly) <= hy) & (fabsf(ddz) <= hz)) {
                const int idx = __float_as_int(q.w);
                const int d   = idx >> 5;
                atomicOr(&s_bits[d + (d >> 4)], 1u << (idx & 31));
            }
        }
    }
    __syncthreads();

    // ordered compaction: thread owns dwords [tid*16, tid*16+16), padded base tid*17
    unsigned v[16];
    int cnt = 0;
    #pragma unroll
    for (int i = 0; i < 16; ++i) {
        v[i] = s_bits[tid * 17 + i];
        cnt += __popc(v[i]);
    }

    int incl = cnt;
    #pragma unroll
    for (int off = 1; off < 64; off <<= 1) {
        const int x = __shfl_up(incl, off, 64);
        if (lane >= off) incl += x;
    }
    if (lane == 63) s_wsum[w] = incl;
    __syncthreads();

    int wpre = 0, total = 0;
    #pragma unroll
    for (int ww = 0; ww < 4; ++ww) {
        const int x = s_wsum[ww];
        if (ww < w) wpre += x;
        total += x;
    }
    int pos = wpre + (incl - cnt);
    const int pn = total < NFPS ? total : NFPS;

    const int obase = box * NFPS;
    #pragma unroll
    for (int t = 0; t < 2; ++t) {                 // zero tail [pn,512)
        const int k = tid + t * NTHR;
        if (k >= pn) out_idx[obase + k] = 0;
    }

    const int pt0 = tid * 512;
    #pragma unroll
    for (int i = 0; i < 16; ++i) {
        unsigned x = v[i];
        while (x) {
            const int bpos = __ffs(x) - 1;
            if (pos < NFPS) out_idx[obase + pos] = pt0 + i * 32 + bpos;
            ++pos;
            x &= x - 1;
        }
    }
    if (tid == 0) out_num[box] = pn;
}

extern "C" void kernel_launch(void* const* d_in, const int* in_sizes, int n_in,
                              void* d_out, int out_size, void* d_ws, size_t ws_size,
                              hipStream_t stream) {
    const float* points = (const float*)d_in[0];   // (N,4) f32
    const float* boxes  = (const float*)d_in[1];   // (B,M,7) f32
    int* out_idx = (int*)d_out;                    // (B,M,512)
    int* out_num = (int*)d_out + NBOX * NFPS;      // (B,M)

    int*    cursor = (int*)d_ws;
    float4* binned = (float4*)((char*)d_ws + BIN_OFF);

    void* args[] = { (void*)&points, (void*)&boxes, (void*)&cursor,
                     (void*)&binned, (void*)&out_idx, (void*)&out_num };
    hipLaunchCooperativeKernel((const void*)roi_all, dim3(NBLK), dim3(NTHR),
                               args, 0, stream);
}

// Round 8
// 38.765 us; speedup vs baseline: 3.4230x; 3.4230x over previous
//
#include <hip/hip_runtime.h>
#include <math.h>

#define NPTS   131072
#define MBOX   128
#define NBOX   256
#define NFPS   512

#define NTHR   1024
#define NWAVE  16
#define PPW    (NPTS / NWAVE)       // 8192 points per wave
#define JITER  (PPW / 64)           // 128
#define DWPB   (NPTS / 32)          // 4096 bitmask dwords per box
#define LDSW   (DWPB + DWPB / 16)   // 4352 (pad: dword d at d + d/16)

__device__ __forceinline__ int padi(int d) { return d + (d >> 4); }

// One block = one box PAIR (2k, 2k+1); block streams ALL points once.
// Wave w owns points [w*8192,(w+1)*8192): its ballot IS the bitmask dwords.
__global__ __launch_bounds__(NTHR)
void roi_one(const float* __restrict__ points,   // (N,4): [b,x,y,z]
             const float* __restrict__ boxes,    // (B,M,7)
             int* __restrict__ out_idx,          // (NBOX, 512)
             int* __restrict__ out_num)          // (NBOX)
{
    const int pair = blockIdx.x;                 // 0..127
    const int tid  = threadIdx.x;
    const int lane = tid & 63;
    const int w    = tid >> 6;

    __shared__ float    s_prm[2][8];
    __shared__ unsigned s_bits[2][LDSW];         // ~34.8 KB
    __shared__ int      s_wsum[2][8];

    // box params -- fp32/f64 ops verbatim from passing kernels (bit-exact)
    if (tid < 2) {
        const int box = pair * 2 + tid;
        const float* bx = boxes + box * 7;
        const float bdx = bx[3], bdy = bx[4], bdz = bx[5], h = bx[6];
        s_prm[tid][0] = bx[0];
        s_prm[tid][1] = bx[1];
        s_prm[tid][2] = bx[2];
        s_prm[tid][3] = __fmul_rn(__fadd_rn(bdy, 2.0f), 0.5f);
        s_prm[tid][4] = __fmul_rn(__fadd_rn(bdx, 2.0f), 0.5f);
        s_prm[tid][5] = __fmul_rn(__fadd_rn(bdz, 2.0f), 0.5f);
        const float hp = -__fadd_rn(h, 1.5707963705062866f);  // fl32(pi/2)
        s_prm[tid][6] = (float)cos((double)hp);
        s_prm[tid][7] = (float)sin((double)hp);
    }
    __syncthreads();

    const float cxA = s_prm[0][0], cyA = s_prm[0][1], czA = s_prm[0][2];
    const float hxA = s_prm[0][3], hyA = s_prm[0][4], hzA = s_prm[0][5];
    const float cA  = s_prm[0][6], sA  = s_prm[0][7];
    const float cxB = s_prm[1][0], cyB = s_prm[1][1], czB = s_prm[1][2];
    const float hxB = s_prm[1][3], hyB = s_prm[1][4], hzB = s_prm[1][5];
    const float cB  = s_prm[1][6], sB  = s_prm[1][7];

    const int bB = pair >> 6;                    // batch of both boxes

    const float4* p4 = (const float4*)points + w * PPW + lane;

    #pragma unroll 1
    for (int jo = 0; jo < JITER; jo += 4) {
        float4 pr[4];
        #pragma unroll
        for (int u = 0; u < 4; ++u) pr[u] = p4[(jo + u) * 64];
        #pragma unroll
        for (int u = 0; u < 4; ++u) {
            const float px = pr[u].y, py = pr[u].z, pz = pr[u].w;
            const unsigned long long bok = __ballot((int)pr[u].x == bB);

            const float dxA = __fsub_rn(px, cxA);
            const float dyA = __fsub_rn(py, cyA);
            const float dzA = __fsub_rn(pz, czA);
            const float lxA = __fadd_rn(__fmul_rn(dxA, cA), __fmul_rn(dyA, sA));
            const float lyA = __fadd_rn(__fmul_rn(-dxA, sA), __fmul_rn(dyA, cA));
            const unsigned long long balA =
                __ballot((fabsf(lxA) <= hxA) & (fabsf(lyA) <= hyA) &
                         (fabsf(dzA) <= hzA)) & bok;

            const float dxB = __fsub_rn(px, cxB);
            const float dyB = __fsub_rn(py, cyB);
            const float dzB = __fsub_rn(pz, czB);
            const float lxB = __fadd_rn(__fmul_rn(dxB, cB), __fmul_rn(dyB, sB));
            const float lyB = __fadd_rn(__fmul_rn(-dxB, sB), __fmul_rn(dyB, cB));
            const unsigned long long balB =
                __ballot((fabsf(lxB) <= hxB) & (fabsf(lyB) <= hyB) &
                         (fabsf(dzB) <= hzB)) & bok;

            if (lane == 0) {
                const int d0 = (w * JITER + jo + u) * 2;   // even
                const int a  = padi(d0);                   // a, a+1 adjacent
                s_bits[0][a]     = (unsigned)balA;
                s_bits[0][a + 1] = (unsigned)(balA >> 32);
                s_bits[1][a]     = (unsigned)balB;
                s_bits[1][a + 1] = (unsigned)(balB >> 32);
            }
        }
    }
    __syncthreads();

    // ---- compaction: waves 0-7 -> box A, waves 8-15 -> box B ----
    const int half = tid >> 9;
    const int t2   = tid & 511;
    const int l2   = t2 & 63;
    const int w2   = t2 >> 6;                    // 0..7

    // thread owns dwords [8*t2, 8*t2+8) (one padded 16-group, contiguous)
    unsigned v[8];
    int cnt = 0;
    #pragma unroll
    for (int i = 0; i < 8; ++i) {
        v[i] = s_bits[half][padi(t2 * 8 + i)];
        cnt += __popc(v[i]);
    }

    int incl = cnt;
    #pragma unroll
    for (int off = 1; off < 64; off <<= 1) {
        const int x = __shfl_up(incl, off, 64);
        if (l2 >= off) incl += x;
    }
    if (l2 == 63) s_wsum[half][w2] = incl;
    __syncthreads();

    int wpre = 0, total = 0;
    #pragma unroll
    for (int ww = 0; ww < 8; ++ww) {
        const int x = s_wsum[half][ww];
        if (ww < w2) wpre += x;
        total += x;
    }
    int pos = wpre + (incl - cnt);
    const int pn = total < NFPS ? total : NFPS;

    const int box   = pair * 2 + half;
    const int obase = box * NFPS;
    if (t2 >= pn) out_idx[obase + t2] = 0;       // zero tail (t2 in [0,512))

    const int pt0 = t2 * 256;
    #pragma unroll
    for (int i = 0; i < 8; ++i) {
        unsigned x = v[i];
        while (x) {
            const int bpos = __ffs(x) - 1;
            if (pos < NFPS) out_idx[obase + pos] = pt0 + i * 32 + bpos;
            ++pos;
            x &= x - 1;
        }
    }
    if (t2 == 0) out_num[box] = pn;
}

extern "C" void kernel_launch(void* const* d_in, const int* in_sizes, int n_in,
                              void* d_out, int out_size, void* d_ws, size_t ws_size,
                              hipStream_t stream) {
    const float* points = (const float*)d_in[0];   // (N,4) f32
    const float* boxes  = (const float*)d_in[1];   // (B,M,7) f32
    int* out_idx = (int*)d_out;                    // (B,M,512)
    int* out_num = (int*)d_out + NBOX * NFPS;      // (B,M)

    roi_one<<<NBOX / 2, NTHR, 0, stream>>>(points, boxes, out_idx, out_num);
}

// Round 9
// 25.258 us; speedup vs baseline: 5.2535x; 1.5348x over previous
//
#include <hip/hip_runtime.h>
#include <math.h>

#define NPTS   131072
#define MBOX   128
#define NBOX   256
#define NFPS   512

#define NTHR   1024
#define NWAVE  16
#define PPW    (NPTS / NWAVE)       // 8192 points per wave
#define NGRP   (PPW / 64)           // 128 ballot-groups per wave
#define DWPB   (NPTS / 32)          // 4096 bitmask dwords per box

// One block = one box; block streams ALL points once (L1-resident stream).
// Each 64-point group's ballot IS the bitmask dword-pair.
__global__ __launch_bounds__(NTHR)
void roi_one(const float* __restrict__ points,   // (N,4): [b,x,y,z]
             const float* __restrict__ boxes,    // (B,M,7)
             int* __restrict__ out_idx,          // (NBOX, 512)
             int* __restrict__ out_num)          // (NBOX)
{
    const int box  = blockIdx.x;                 // 0..255
    const int tid  = threadIdx.x;
    const int lane = tid & 63;
    const int w    = tid >> 6;

    __shared__ float    s_prm[8];
    __shared__ unsigned s_bits[DWPB];            // 16 KB, linear (b128-aligned)
    __shared__ int      s_wsum[NWAVE];

    // issue first batch of loads BEFORE the param barrier (latency overlap)
    const float4* p4 = (const float4*)points + w * PPW + lane;
    float4 A[4], B[4];
    #pragma unroll
    for (int u = 0; u < 4; ++u) A[u] = p4[u * 64];

    // box params -- fp32/f64 ops verbatim from passing kernels (bit-exact)
    if (tid == 0) {
        const float* bx = boxes + box * 7;
        const float bdx = bx[3], bdy = bx[4], bdz = bx[5], h = bx[6];
        s_prm[0] = bx[0];
        s_prm[1] = bx[1];
        s_prm[2] = bx[2];
        s_prm[3] = __fmul_rn(__fadd_rn(bdy, 2.0f), 0.5f);
        s_prm[4] = __fmul_rn(__fadd_rn(bdx, 2.0f), 0.5f);
        s_prm[5] = __fmul_rn(__fadd_rn(bdz, 2.0f), 0.5f);
        const float hp = -__fadd_rn(h, 1.5707963705062866f);  // fl32(pi/2)
        s_prm[6] = (float)cos((double)hp);
        s_prm[7] = (float)sin((double)hp);
    }
    __syncthreads();

    const float cx = s_prm[0], cy = s_prm[1], cz = s_prm[2];
    const float hx = s_prm[3], hy = s_prm[4], hz = s_prm[5];
    const float c  = s_prm[6], s  = s_prm[7];
    const float bBf = (float)(box >> 7);         // batch as exact float 0/1

    // ping-pong pipeline: compute batch while next batch's loads are in flight
    #pragma unroll 1
    for (int jo = 0; jo < NGRP; jo += 8) {
        unsigned long long bal8[8];

        #pragma unroll
        for (int u = 0; u < 4; ++u) B[u] = p4[(jo + 4 + u) * 64];

        #pragma unroll
        for (int u = 0; u < 4; ++u) {
            const float4 q = A[u];
            const float dx = __fsub_rn(q.y, cx);
            const float dy = __fsub_rn(q.z, cy);
            const float dz = __fsub_rn(q.w, cz);
            const float lx = __fadd_rn(__fmul_rn(dx, c), __fmul_rn(dy, s));
            const float ly = __fadd_rn(__fmul_rn(-dx, s), __fmul_rn(dy, c));
            bal8[u] = __ballot((q.x == bBf) & (fabsf(lx) <= hx) &
                               (fabsf(ly) <= hy) & (fabsf(dz) <= hz));
        }

        if (jo + 8 < NGRP) {
            #pragma unroll
            for (int u = 0; u < 4; ++u) A[u] = p4[(jo + 8 + u) * 64];
        }

        #pragma unroll
        for (int u = 0; u < 4; ++u) {
            const float4 q = B[u];
            const float dx = __fsub_rn(q.y, cx);
            const float dy = __fsub_rn(q.z, cy);
            const float dz = __fsub_rn(q.w, cz);
            const float lx = __fadd_rn(__fmul_rn(dx, c), __fmul_rn(dy, s));
            const float ly = __fadd_rn(__fmul_rn(-dx, s), __fmul_rn(dy, c));
            bal8[4 + u] = __ballot((q.x == bBf) & (fabsf(lx) <= hx) &
                                   (fabsf(ly) <= hy) & (fabsf(dz) <= hz));
        }

        // 16 consecutive dwords, one branch per 512 points, 4x ds_write_b128
        if (lane == 0) {
            uint4* dst = (uint4*)&s_bits[w * (NGRP * 2) + jo * 2];
            #pragma unroll
            for (int u = 0; u < 4; ++u)
                dst[u] = make_uint4((unsigned)bal8[2*u],
                                    (unsigned)(bal8[2*u] >> 32),
                                    (unsigned)bal8[2*u + 1],
                                    (unsigned)(bal8[2*u + 1] >> 32));
        }
    }
    __syncthreads();

    // ---- ordered compaction: thread t owns dwords [4t,4t+4) = points [128t,128t+128)
    const uint4 qv = ((const uint4*)s_bits)[tid];     // conflict-free b128
    unsigned v[4] = {qv.x, qv.y, qv.z, qv.w};
    int cnt = __popc(v[0]) + __popc(v[1]) + __popc(v[2]) + __popc(v[3]);

    int incl = cnt;
    #pragma unroll
    for (int off = 1; off < 64; off <<= 1) {
        const int x = __shfl_up(incl, off, 64);
        if (lane >= off) incl += x;
    }
    if (lane == 63) s_wsum[w] = incl;
    __syncthreads();

    int wpre = 0, total = 0;
    #pragma unroll
    for (int ww = 0; ww < NWAVE; ++ww) {
        const int x = s_wsum[ww];
        if (ww < w) wpre += x;
        total += x;
    }
    int pos = wpre + (incl - cnt);
    const int pn = total < NFPS ? total : NFPS;

    const int obase = box * NFPS;
    if (tid < NFPS && tid >= pn) out_idx[obase + tid] = 0;   // zero tail

    const int pt0 = tid * 128;
    #pragma unroll
    for (int i = 0; i < 4; ++i) {
        unsigned x = v[i];
        while (x) {
            const int bpos = __ffs(x) - 1;
            if (pos < NFPS) out_idx[obase + pos] = pt0 + i * 32 + bpos;
            ++pos;
            x &= x - 1;
        }
    }
    if (tid == 0) out_num[box] = pn;
}

extern "C" void kernel_launch(void* const* d_in, const int* in_sizes, int n_in,
                              void* d_out, int out_size, void* d_ws, size_t ws_size,
                              hipStream_t stream) {
    const float* points = (const float*)d_in[0];   // (N,4) f32
    const float* boxes  = (const float*)d_in[1];   // (B,M,7) f32
    int* out_idx = (int*)d_out;                    // (B,M,512)
    int* out_num = (int*)d_out + NBOX * NFPS;      // (B,M)

    roi_one<<<NBOX, NTHR, 0, stream>>>(points, boxes, out_idx, out_num);
}